// Round 6
// baseline (185.010 us; speedup 1.0000x reference)
//
#include <hip/hip_runtime.h>
#include <hip/hip_bf16.h>
#include <cstdint>

// LSTM cell: g[g,b,n] = sum_k A[b,k] * Wcat[g,k,n],  A = [x | h]  (K = 2048)
// i,f,o = sigmoid(g0,1,2), u = tanh(g3), c_t = i*u + f*c, h_t = o*tanh(c_t)
// Round 6: counted-vmcnt 2-phase schedule at 2 BLOCKS/CU (64 KB LDS).
// Theory: rounds 1/5 both plateaued at ~39% MfmaUtil with 8 waves/CU because
// phase stalls were either long (r1: vmcnt(0) drains) or un-hidden (r5:
// 1 block/CU lockstep). Short counted stalls + a co-resident independent
// block = m114 overlap mechanism.

#define LDS_TOTAL 65536     // 2 buf x (A[128][64] 16KB + B[4][32][64] 16KB)

typedef __attribute__((ext_vector_type(8))) short bf16x8;   // 8 bf16 = 4 VGPR
typedef __attribute__((ext_vector_type(4))) float f32x4;
typedef __attribute__((ext_vector_type(4))) unsigned int u32x4;

static __device__ __forceinline__ unsigned short f2bf(float f) {
  union { float f; unsigned int u; } v; v.f = f;
  unsigned int u = v.u;
  unsigned int r = (u + 0x7FFFu + ((u >> 16) & 1u)) >> 16;  // RTN-even
  return (unsigned short)r;
}

static __device__ __forceinline__ void load16(const void* gp, void* lp) {
  __builtin_amdgcn_global_load_lds(
      (const __attribute__((address_space(1))) void*)gp,
      (__attribute__((address_space(3))) void*)lp, 16, 0, 0);
}

static __device__ __forceinline__ float sigmoid_f(float x) {
  return 1.0f / (1.0f + __expf(-x));
}
static __device__ __forceinline__ float tanh_f(float x) {
  float e = __expf(-2.0f * fabsf(x));
  float r = (1.0f - e) / (1.0f + e);
  return copysignf(r, x);
}

// ---- prep 1: pack A = [x | h] as bf16 [8192][2048] ----
__global__ __launch_bounds__(256) void pack_a_kernel(
    const float* __restrict__ x, const float* __restrict__ h,
    unsigned short* __restrict__ Apack) {
  int t = blockIdx.x * 256 + threadIdx.x;
  size_t base = (size_t)t * 8;
  int b = (int)(base >> 11);
  int k = (int)(base & 2047);
  const float* src = (k < 1024) ? (x + (size_t)b * 1024 + k)
                                : (h + (size_t)b * 1024 + (k - 1024));
  float4 v0 = ((const float4*)src)[0];
  float4 v1 = ((const float4*)src)[1];
  union { unsigned short s[8]; u32x4 v; } o;
  o.s[0] = f2bf(v0.x); o.s[1] = f2bf(v0.y); o.s[2] = f2bf(v0.z); o.s[3] = f2bf(v0.w);
  o.s[4] = f2bf(v1.x); o.s[5] = f2bf(v1.y); o.s[6] = f2bf(v1.z); o.s[7] = f2bf(v1.w);
  *(u32x4*)(Apack + base) = o.v;
}

// ---- prep 2: Wt[g][n][k] = bf16( k<1024 ? Wx[g][k][n] : Wh[g][k-1024][n] ) ----
__global__ __launch_bounds__(256) void prep_w_kernel(
    const float* __restrict__ Wx, const float* __restrict__ Wh,
    unsigned short* __restrict__ Wt) {
  __shared__ float tile[32][33];
  int bid = blockIdx.x;
  int g = bid >> 11;
  int rem = bid & 2047;
  int kt = rem >> 5;
  int nt = rem & 31;
  int k0 = kt * 32, n0 = nt * 32;
  int tx = threadIdx.x & 31, ty = threadIdx.x >> 5;
  const float* Wsrc;
  int ks;
  if (k0 < 1024) { Wsrc = Wx + (size_t)g * 1048576; ks = k0; }
  else           { Wsrc = Wh + (size_t)g * 1048576; ks = k0 - 1024; }
  #pragma unroll
  for (int s = 0; s < 4; ++s) {
    int r = ty + s * 8;
    tile[r][tx] = Wsrc[(size_t)(ks + r) * 1024 + n0 + tx];
  }
  __syncthreads();
  #pragma unroll
  for (int s = 0; s < 4; ++s) {
    int r = ty + s * 8;
    Wt[(size_t)((g << 10) + n0 + r) * 2048 + k0 + tx] = f2bf(tile[tx][r]);
  }
}

// ---- main: fused 4-gate GEMM + LSTM epilogue ----
// 256 thr = 4 waves: wr=w>>1 (rows wr*64..+64), wc=w&1 (n wc*16..+16 per gate).
// Buf (32KB): A[128][64] @0, B[4][32][64] @16384 (gate g @ +g*4096).
// K-step t (2 phases): P1 reads A-all + B-g01, stages B1(t+1)->bufn;
// P2 reads B-g23, stages A(t+2)+B0(t+2)->bufc; vmcnt(6) at end (counted, T4).
__global__ __launch_bounds__(256, 2) void lstm_gemm_kernel(
    const unsigned short* __restrict__ Apack,   // [8192][2048] bf16
    const unsigned short* __restrict__ Wt,      // [4][1024][2048] bf16 (B^T)
    const float* __restrict__ cprev,
    float* __restrict__ out) {
  extern __shared__ char lds[];
  const int tid = threadIdx.x;
  const int l = tid & 63;
  const int w = tid >> 6;              // 0..3
  const int wr = w >> 1;               // 0..1
  const int wc = w & 1;                // 0..1
  const int bid0 = blockIdx.x;
  const int bid = (bid0 & 7) * 256 + (bid0 >> 3);  // XCD swizzle (2048%8==0)
  const int mt = bid >> 5;             // 64 m-tiles
  const int nt = bid & 31;             // 32 n-tiles
  const int m0 = mt << 7;
  const int n0 = nt << 5;

  char* const buf0 = lds;
  char* const buf1 = lds + 32768;

  f32x4 acc[4][4];                     // [m-frag][gate]
  #pragma unroll
  for (int mf = 0; mf < 4; ++mf)
    #pragma unroll
    for (int g = 0; g < 4; ++g) acc[mf][g] = (f32x4)0.0f;

  bf16x8 aR[4][2];                     // m-frags [i][kk], live across P1+P2
  bf16x8 bR[4][2];                     // gates [g][kk]: g01 from P1, g23 from P2

  const int lr = l & 15;
  const int kgrp = (l >> 4) << 4;      // 0/16/32/48 byte k-group
  const int sx = (lr & 7) << 4;        // XOR swizzle (row&7 == lr&7 everywhere)
  const int kx0 = kgrp ^ sx;
  const int kx1 = (64 + kgrp) ^ sx;
  const int aoff = (wr * 64 + lr) * 128;
  const int boff = 16384 + (wc * 16 + lr) * 128;

  // Hoisted stage bases (verified r5 scheme): chunk c = p*256+tid, byte=c*16,
  // row = c/8 = p*32 + tid/8; (row&7) = (tid>>3)&7, kb depends only on tid.
  const int arl = tid >> 3;                          // 0..31
  const int akb = ((tid << 4) & 127) ^ ((arl & 7) << 4);
  const unsigned short* const gAbase =
      Apack + (size_t)(m0 + arl) * 2048 + (akb >> 1);
  const unsigned short* const gBbase =
      Wt + (size_t)(n0 + arl) * 2048 + (akb >> 1);
  const int dbase = (tid & ~63) << 4;

  auto stageA = [&](char* bufb, int t) {             // A both halves: 4 loads
    const unsigned short* g0 = gAbase + (t << 6);
    load16(g0,          bufb + dbase);               // rows  0-31
    load16(g0 +  65536, bufb + dbase + 4096);        // rows 32-63
    load16(g0 + 131072, bufb + dbase + 8192);        // rows 64-95
    load16(g0 + 196608, bufb + dbase + 12288);       // rows 96-127
  };
  auto stageB0 = [&](char* bufb, int t) {            // gates 0,1: 2 loads
    const unsigned short* g0 = gBbase + (t << 6);
    load16(g0,           bufb + 16384 + dbase);
    load16(g0 + 2097152, bufb + 20480 + dbase);
  };
  auto stageB1 = [&](char* bufb, int t) {            // gates 2,3: 2 loads
    const unsigned short* g0 = gBbase + (size_t)2 * 2097152 + (t << 6);
    load16(g0,           bufb + 24576 + dbase);
    load16(g0 + 2097152, bufb + 28672 + dbase);
  };

  auto readA = [&](const char* bufc) {               // 8 ds_read_b128
    #pragma unroll
    for (int i = 0; i < 4; ++i) {
      const char* p = bufc + aoff + i * 2048;
      aR[i][0] = *(const bf16x8*)(p + kx0);
      aR[i][1] = *(const bf16x8*)(p + kx1);
    }
  };
  auto readB = [&](const char* bufc, int gh) {       // 4 ds_read_b128
    #pragma unroll
    for (int i = 0; i < 2; ++i) {
      const char* p = bufc + boff + (gh * 2 + i) * 4096;
      bR[gh * 2 + i][0] = *(const bf16x8*)(p + kx0);
      bR[gh * 2 + i][1] = *(const bf16x8*)(p + kx1);
    }
  };
  auto mfma16 = [&](int gh) {                        // 16 MFMA (all m, 2 gates)
    __builtin_amdgcn_s_setprio(1);
    #pragma unroll
    for (int kk = 0; kk < 2; ++kk)
      #pragma unroll
      for (int i = 0; i < 4; ++i)
        #pragma unroll
        for (int gg = 0; gg < 2; ++gg)
          acc[i][gh * 2 + gg] = __builtin_amdgcn_mfma_f32_16x16x32_bf16(
              aR[i][kk], bR[gh * 2 + gg][kk], acc[i][gh * 2 + gg], 0, 0, 0);
    __builtin_amdgcn_s_setprio(0);
  };

  // Prologue: t=0 full (8 loads) -> buf0; t=1 A+B0 (6) -> buf1; B1(1) comes
  // from P1(0). vmcnt(6): t=0's 8 landed, t=1's 6 in flight.
  stageA(buf0, 0); stageB0(buf0, 0); stageB1(buf0, 0);
  stageA(buf1, 1); stageB0(buf1, 1);
  asm volatile("s_waitcnt vmcnt(6)" ::: "memory");
  __builtin_amdgcn_s_barrier();

  auto kstep = [&](int t, char* bufc, char* bufn) {
    // ---- P1: all A-frags + gates 0,1 ----
    readA(bufc);                                     // 8 reads
    readB(bufc, 0);                                  // 4 reads
    if (t + 1 < 32) stageB1(bufn, t + 1);            // B1(t-1) reads done @P2(t-1) bar2
    asm volatile("s_waitcnt lgkmcnt(8)" ::: "memory");
    __builtin_amdgcn_s_barrier();
    asm volatile("s_waitcnt lgkmcnt(0)" ::: "memory");
    mfma16(0);
    __builtin_amdgcn_s_barrier();                    // all A,B0(t) reads complete
    // ---- P2: gates 2,3 ----
    readB(bufc, 1);                                  // 4 reads
    if (t + 2 < 32) { stageA(bufc, t + 2); stageB0(bufc, t + 2); }  // regions free
    __builtin_amdgcn_s_barrier();
    asm volatile("s_waitcnt lgkmcnt(0)" ::: "memory");
    mfma16(1);
    // Counted wait (T4): drains through tile t+1's 8 halves; leaves t+2's
    // A+B0 (6) in flight. Tail: t>=30 drains all.
    if (t < 30) asm volatile("s_waitcnt vmcnt(6)" ::: "memory");
    else        asm volatile("s_waitcnt vmcnt(0)" ::: "memory");
    __builtin_amdgcn_s_barrier();
  };

  #pragma unroll 1
  for (int tt = 0; tt < 16; ++tt) {
    kstep(2 * tt,     buf0, buf1);
    kstep(2 * tt + 1, buf1, buf0);
  }

  // Epilogue: C/D layout col = lane&15, row = (lane>>4)*4 + reg  [m89]
  const int q = (l >> 4) << 2;
  const int col = n0 + wc * 16 + lr;
  #pragma unroll
  for (int mf = 0; mf < 4; ++mf) {
    #pragma unroll
    for (int j = 0; j < 4; ++j) {
      int row = m0 + wr * 64 + mf * 16 + q + j;
      float gi = acc[mf][0][j];
      float gf = acc[mf][1][j];
      float go = acc[mf][2][j];
      float gu = acc[mf][3][j];
      float i_ = sigmoid_f(gi);
      float f_ = sigmoid_f(gf);
      float o_ = sigmoid_f(go);
      float u_ = tanh_f(gu);
      size_t idx = (size_t)row * 1024 + col;
      float ct = i_ * u_ + f_ * cprev[idx];
      float ht = o_ * tanh_f(ct);
      out[idx] = ht;                   // h_t
      out[8388608 + idx] = ct;         // c_t
    }
  }
}

extern "C" void kernel_launch(void* const* d_in, const int* in_sizes, int n_in,
                              void* d_out, int out_size, void* d_ws, size_t ws_size,
                              hipStream_t stream) {
  const float* x  = (const float*)d_in[0];
  const float* h  = (const float*)d_in[1];
  const float* c  = (const float*)d_in[2];
  const float* Wx = (const float*)d_in[3];
  const float* Wh = (const float*)d_in[4];
  float* out = (float*)d_out;

  unsigned short* Apack = (unsigned short*)d_ws;                  // 33,554,432 B
  unsigned short* Wt = (unsigned short*)((char*)d_ws + 33554432); // 16,777,216 B

  pack_a_kernel<<<8192, 256, 0, stream>>>(x, h, Apack);
  prep_w_kernel<<<8192, 256, 0, stream>>>(Wx, Wh, Wt);
  lstm_gemm_kernel<<<dim3(2048), dim3(256), LDS_TOTAL, stream>>>(Apack, Wt, c, out);
}